// Round 9
// baseline (113.254 us; speedup 1.0000x reference)
//
#include <hip/hip_runtime.h>
#include <hip/hip_bf16.h>
#include <cstdint>

// Problem constants
#define Bn 8
#define Cn 64
#define Hn 112
#define Wn 112
#define On 64
#define Ln (Hn * Wn)   // 12544 = 98 * 128
#define HP 114
#define WP 114

typedef __attribute__((ext_vector_type(4)))  float f32x4;
typedef __attribute__((ext_vector_type(16))) float f32x16;
typedef __attribute__((ext_vector_type(8)))  short bf16x8;
typedef __attribute__((ext_vector_type(4)))  unsigned int u32x4;

__device__ __forceinline__ unsigned f2bf(float f) {
    unsigned u = __float_as_uint(f);
    unsigned r = 0x7fffu + ((u >> 16) & 1u);
    return (u + r) >> 16;   // RNE bf16 in low 16 bits
}

// -----------------------------------------------------------------------------
// Kernel 1 (fused prep):
//  blocks [0,912):  x [B][C][112][112] f32 -> xps: padded LINEAR NHWC bf16,
//    xps[((b*114 + row)*114 + wp)*64 + c]  (zero border).
//  blocks [912,948): weight [O][C][3][3] f32 -> wpk bf16 A-fragments for
//    v_mfma_f32_32x32x16_bf16: fidx = p*8 + wr*4 + kc; per lane:
//    o = wr*32 + (lane&31), c = kc*16 + (lane>>5)*8 + j (j=0..7).
// -----------------------------------------------------------------------------
__global__ __launch_bounds__(128) void prep_kernel(const float* __restrict__ x,
                                                   const float* __restrict__ w,
                                                   unsigned short* __restrict__ xps,
                                                   unsigned short* __restrict__ wpk) {
    int blk = blockIdx.x;
    int t = threadIdx.x;
    if (blk < 912) {
        int b = blk / HP, row = blk - b * HP;   // padded row index
        int c8  = t >> 4;                       // 0..7 channel octet
        int wpl = t & 15;
        int h = row - 1;                        // input row
        const float* xb = x + (size_t)b * Cn * Hn * Wn;
        unsigned short* dst = xps + ((size_t)(b * HP + row) * WP) * Cn;
#pragma unroll
        for (int g = 0; g < 8; ++g) {
            int wp = wpl + (g << 4);
            if (wp < WP) {
                int wcol = wp - 1;
                bool inb = ((unsigned)h < (unsigned)Hn) & ((unsigned)wcol < (unsigned)Wn);
                const float* s = xb + ((size_t)(c8 * 8) * Hn + (inb ? h : 0)) * Wn + (inb ? wcol : 0);
                unsigned pk[4];
#pragma unroll
                for (int j = 0; j < 4; ++j) {
                    float v0 = s[(size_t)(2 * j)     * (Hn * Wn)];
                    float v1 = s[(size_t)(2 * j + 1) * (Hn * Wn)];
                    if (!inb) { v0 = 0.f; v1 = 0.f; }
                    pk[j] = f2bf(v0) | (f2bf(v1) << 16);
                }
                u32x4 v; v[0] = pk[0]; v[1] = pk[1]; v[2] = pk[2]; v[3] = pk[3];
                *reinterpret_cast<u32x4*>(dst + (size_t)wp * Cn + c8 * 8) = v;
            }
        }
    } else {
        int idx = (blk - 912) * 2 + (t >> 6);   // 0..71 = p*8 + wr*4 + kc
        int lane = t & 63;
        int kc = idx & 3, wr2 = (idx >> 2) & 1, p = idx >> 3;
        int o  = wr2 * 32 + (lane & 31);
        int cb = kc * 16 + (lane >> 5) * 8;
        unsigned pk[4];
#pragma unroll
        for (int j = 0; j < 4; ++j) {
            float v0 = w[((size_t)o * Cn + cb + 2 * j) * 9 + p];
            float v1 = w[((size_t)o * Cn + cb + 2 * j + 1) * 9 + p];
            pk[j] = f2bf(v0) | (f2bf(v1) << 16);
        }
        u32x4 v; v[0] = pk[0]; v[1] = pk[1]; v[2] = pk[2]; v[3] = pk[3];
        reinterpret_cast<u32x4*>(wpk)[idx * 64 + lane] = v;
    }
}

// -----------------------------------------------------------------------------
// Kernel 2: implicit-GEMM conv, 32x32x16 MFMA, per-pixel tap mask — NO LDS.
// B-fragments load directly from the padded NHWC bf16 xps (L1/L2-hot: the
// per-image slab is 1.66MB, fits the pinned XCD's 4MB L2; per-block working
// set ~58KB streams through L1). No staging chain, no __syncthreads ->
// purely TLP-hidden latency at 4 blocks/CU (16 waves/CU).
// Block = 256 thr (4 waves); each wave owns one 32-px tile and ALL 64 output
// channels (acc0/acc1). A-fragments double-buffered one tap ahead from wpk.
// Taps are pure global address offsets (pad folded into xps).
// XCD pinning: b = blockIdx.x & 7.
// -----------------------------------------------------------------------------
__global__ __launch_bounds__(256, 4) void conv_direct(const unsigned short* __restrict__ xps,
                                                      const unsigned short* __restrict__ wpk,
                                                      const int* __restrict__ mask_idx,
                                                      float* __restrict__ out) {
    int b  = blockIdx.x & 7;                // image -> XCD pin
    int lt = blockIdx.x >> 3;               // 0..97
    int l0 = lt * 128;

    int tid  = threadIdx.x;
    int wave = tid >> 6, lane = tid & 63;   // wave = px-tile 0..3
    int hi = lane >> 5;
    int li = lane & 31;

    int lg = l0 + wave * 32 + li;           // this lane's pixel
    int oh = lg / Wn, ow = lg - oh * Wn;
    int mv = mask_idx[lg];

    // Patch base in padded coords: input rows oh..oh+2, cols ow..ow+2 (pad folded).
    const char* xb = (const char*)(xps + ((size_t)(b * HP + oh) * WP + ow) * Cn)
                   + hi * 16;

    const u32x4* wv = reinterpret_cast<const u32x4*>(wpk);
    const u32x4 vzero = {0u, 0u, 0u, 0u};

    // A-fragment double buffer: 8 frags per tap (wr0 kc0..3, wr1 kc0..3).
    u32x4 af0[8], af1[8];
#pragma unroll
    for (int f = 0; f < 8; ++f) af0[f] = wv[f * 64 + lane];   // tap p=0

    f32x16 acc0 = {}, acc1 = {};

#pragma unroll
    for (int p = 0; p < 9; ++p) {
        // Fully-unrolled: (p&1) compile-time -> static buffer select.
        u32x4* cur = (p & 1) ? af1 : af0;
        u32x4* nxt = (p & 1) ? af0 : af1;
        if (p < 8) {
#pragma unroll
            for (int f = 0; f < 8; ++f)
                nxt[f] = wv[((p + 1) * 8 + f) * 64 + lane];
        }

        int dh = p / 3, dw = p - dh * 3;
        const char* bp = xb + (dh * WP + dw) * (Cn * 2);   // tap offset in bytes
        u32x4 bv[4];
#pragma unroll
        for (int kc = 0; kc < 4; ++kc)
            bv[kc] = *reinterpret_cast<const u32x4*>(bp + kc * 32);
        if (mv == p) { bv[0] = vzero; bv[1] = vzero; bv[2] = vzero; bv[3] = vzero; }

#pragma unroll
        for (int kc = 0; kc < 4; ++kc) {
            bf16x8 bb = *reinterpret_cast<bf16x8*>(&bv[kc]);
            bf16x8 a0 = *reinterpret_cast<bf16x8*>(&cur[kc]);
            bf16x8 a1 = *reinterpret_cast<bf16x8*>(&cur[4 + kc]);
            acc0 = __builtin_amdgcn_mfma_f32_32x32x16_bf16(a0, bb, acc0, 0, 0, 0);
            acc1 = __builtin_amdgcn_mfma_f32_32x32x16_bf16(a1, bb, acc1, 0, 0, 0);
        }
    }

    // Epilogue: D col=lane&31 (=pixel), row=(reg&3)+8*(reg>>2)+4*hi (=o).
    float* ob = out + (size_t)(b * On) * Ln + lg;
#pragma unroll
    for (int reg = 0; reg < 16; ++reg) {
        int orow = (reg & 3) + 8 * (reg >> 2) + 4 * hi;
        ob[(size_t)orow * Ln]        = acc0[reg];
        ob[(size_t)(orow + 32) * Ln] = acc1[reg];
    }
}

// -----------------------------------------------------------------------------
extern "C" void kernel_launch(void* const* d_in, const int* in_sizes, int n_in,
                              void* d_out, int out_size, void* d_ws, size_t ws_size,
                              hipStream_t stream) {
    const float* x    = (const float*)d_in[0];
    const float* w    = (const float*)d_in[1];
    const int*   mask = (const int*)d_in[2];
    float* out = (float*)d_out;

    unsigned short* xps = (unsigned short*)d_ws;                     // 13,307,904 B
    unsigned short* wpk = (unsigned short*)((char*)d_ws + 13307904); // +73,728 B

    prep_kernel<<<948,     128, 0, stream>>>(x, w, xps, wpk);
    conv_direct<<<Bn * 98, 256, 0, stream>>>(xps, wpk, mask, out);
}

// Round 10
// 98.357 us; speedup vs baseline: 1.1515x; 1.1515x over previous
//
#include <hip/hip_runtime.h>
#include <hip/hip_bf16.h>
#include <cstdint>

// Problem constants
#define Bn 8
#define Cn 64
#define Hn 112
#define Wn 112
#define On 64
#define Ln (Hn * Wn)   // 12544
#define HP 114
#define WP 114

typedef __attribute__((ext_vector_type(4)))  float f32x4;
typedef __attribute__((ext_vector_type(16))) float f32x16;
typedef __attribute__((ext_vector_type(8)))  short bf16x8;
typedef __attribute__((ext_vector_type(4)))  unsigned int u32x4;

typedef __attribute__((address_space(3))) unsigned int lds_u32;
typedef __attribute__((address_space(1))) const unsigned int glob_u32;

__device__ __forceinline__ unsigned f2bf(float f) {
    unsigned u = __float_as_uint(f);
    unsigned r = 0x7fffu + ((u >> 16) & 1u);
    return (u + r) >> 16;   // RNE bf16 in low 16 bits
}

// -----------------------------------------------------------------------------
// Kernel 1 (fused prep) — VERBATIM from R5 (passed, absmax 0.5):
//  blocks [0,912):  x [B][C][112][112] f32 -> xps: padded NHWC bf16 with the
//    LDS slot-permutation PRE-APPLIED: chunk = ((b*114+row)*114 + wp)*8 +
//    (c8 ^ (wp&7)), 16B chunks. conv stages with global_load_lds into LINEAR
//    LDS and reads with the matching XOR (both-sides rule via source perm).
//  blocks [912,948): weight -> wpk bf16 A-fragments, fidx = p*8 + wr*4 + kc;
//    per lane: o = wr*32 + (lane&31), c = kc*16 + (lane>>5)*8 + j.
// -----------------------------------------------------------------------------
__global__ __launch_bounds__(128) void prep_kernel(const float* __restrict__ x,
                                                   const float* __restrict__ w,
                                                   unsigned short* __restrict__ xps,
                                                   unsigned short* __restrict__ wpk) {
    int blk = blockIdx.x;
    int t = threadIdx.x;
    if (blk < 912) {
        int b = blk / HP, row = blk - b * HP;   // padded row index
        int c8  = t >> 4;                       // 0..7 channel octet
        int wpl = t & 15;
        int h = row - 1;                        // input row
        const float* xb = x + (size_t)b * Cn * Hn * Wn;
        unsigned short* dst = xps + ((size_t)(b * HP + row) * WP) * Cn;
#pragma unroll
        for (int g = 0; g < 8; ++g) {
            int wp = wpl + (g << 4);
            if (wp < WP) {
                int wcol = wp - 1;
                bool inb = ((unsigned)h < (unsigned)Hn) & ((unsigned)wcol < (unsigned)Wn);
                const float* s = xb + ((size_t)(c8 * 8) * Hn + (inb ? h : 0)) * Wn + (inb ? wcol : 0);
                unsigned pk[4];
#pragma unroll
                for (int j = 0; j < 4; ++j) {
                    float v0 = s[(size_t)(2 * j)     * (Hn * Wn)];
                    float v1 = s[(size_t)(2 * j + 1) * (Hn * Wn)];
                    if (!inb) { v0 = 0.f; v1 = 0.f; }
                    pk[j] = f2bf(v0) | (f2bf(v1) << 16);
                }
                int slot = c8 ^ (wp & 7);       // pre-applied swizzle
                u32x4 v; v[0] = pk[0]; v[1] = pk[1]; v[2] = pk[2]; v[3] = pk[3];
                *reinterpret_cast<u32x4*>(dst + ((size_t)wp * 8 + slot) * 8) = v;
            }
        }
    } else {
        int idx = (blk - 912) * 2 + (t >> 6);   // 0..71 = p*8 + wr*4 + kc
        int lane = t & 63;
        int kc = idx & 3, wr2 = (idx >> 2) & 1, p = idx >> 3;
        int o  = wr2 * 32 + (lane & 31);
        int cb = kc * 16 + (lane >> 5) * 8;
        unsigned pk[4];
#pragma unroll
        for (int j = 0; j < 4; ++j) {
            float v0 = w[((size_t)o * Cn + cb + 2 * j) * 9 + p];
            float v1 = w[((size_t)o * Cn + cb + 2 * j + 1) * 9 + p];
            pk[j] = f2bf(v0) | (f2bf(v1) << 16);
        }
        u32x4 v; v[0] = pk[0]; v[1] = pk[1]; v[2] = pk[2]; v[3] = pk[3];
        reinterpret_cast<u32x4*>(wpk)[idx * 64 + lane] = v;
    }
}

// -----------------------------------------------------------------------------
// Kernel 2: pipelined implicit-GEMM conv, 32x32x16 MFMA, per-pixel tap mask.
// 224 blocks (8 img x 28 row-quads), 512 thr, __launch_bounds__(512,2):
// 1 block/CU, 256-VGPR budget, ALL blocks co-resident (one generation).
// Per block: 2 row-pair tiles, double-buffered 58.4KB LDS (116.7KB total).
//   - A-fragments: each wave hoists its 36 frags (wr half) to 144 VGPRs ONCE,
//     reused across both tiles -> no per-tap global A chain, no L2 churn.
//   - Staging: global_load_lds dwordx4 from pre-swizzled xps into linear LDS
//     (zero VALU/VGPR). Tile1's DMAs issue BEFORE tile0's compute (T3 recipe);
//     __syncthreads' vmcnt(0) drain is the only wait.
// Wavegrid 2(O) x 4(px); per tile 2 passes (7 px-tiles of 32). Taps are pure
// LDS address shifts with the verified XOR read swizzle. XCD pin: b = blk&7.
// -----------------------------------------------------------------------------
__global__ __launch_bounds__(512, 2) void conv_pipe(const unsigned short* __restrict__ xps,
                                                    const unsigned short* __restrict__ wpk,
                                                    const int* __restrict__ mask_idx,
                                                    float* __restrict__ out) {
    __shared__ char xs[2][4 * WP * Cn * 2];   // 2 x 58368 B

    int b  = blockIdx.x & 7;                  // image -> XCD pin
    int rq = blockIdx.x >> 3;                 // 0..27 row-quad
    int tid  = threadIdx.x;
    int wave = tid >> 6, lane = tid & 63;
    int wr = wave >> 2;                       // 0..1 : o block of 32
    int wc = wave & 3;                        // 0..3 : px-tile column
    int hi = lane >> 5;
    int li = lane & 31;

#define STAGE(TB, OHP) do {                                                        \
    const char* gsrc_ = (const char*)(xps + ((size_t)(b * HP + (OHP)) * WP) * Cn); \
    int cb0_ = wave * 456;                                                         \
    _Pragma("unroll")                                                              \
    for (int i_ = 0; i_ < 8; ++i_) {                                               \
        int cb_ = cb0_ + i_ * 64;                                                  \
        if (i_ < 7 || lane < 8) {                                                  \
            __builtin_amdgcn_global_load_lds(                                      \
                (glob_u32*)(gsrc_ + ((size_t)(cb_ + lane) << 4)),                  \
                reinterpret_cast<lds_u32*>(reinterpret_cast<uintptr_t>(            \
                    &xs[TB][0] + ((size_t)cb_ << 4))),                             \
                16, 0, 0);                                                         \
        }                                                                          \
    }                                                                              \
} while (0)

    // Issue tile-0 staging DMAs first (earliest start).
    STAGE(0, rq * 4);

    // A-hoist: this wave's 36 fragments, once per block (parallel L2 loads).
    const u32x4* wv = reinterpret_cast<const u32x4*>(wpk);
    u32x4 af[9][4];
#pragma unroll
    for (int p = 0; p < 9; ++p)
#pragma unroll
        for (int kc = 0; kc < 4; ++kc)
            af[p][kc] = wv[(p * 8 + wr * 4 + kc) * 64 + lane];

    // Per-(tile, pass) pixel geometry + mask (loaded up front).
    int mv[2][2], rr[2][2], oww[2][2], lgg[2][2];
#pragma unroll
    for (int t = 0; t < 2; ++t)
#pragma unroll
        for (int s = 0; s < 2; ++s) {
            int tl = wc + 4 * s;
            if (tl < 7) {
                int idx = tl * 32 + li;           // 0..223 within row pair
                int r   = (idx >= Wn) ? 1 : 0;
                rr[t][s]  = r;
                oww[t][s] = idx - r * Wn;
                lgg[t][s] = (rq * 4 + 2 * t) * Wn + idx;
                mv[t][s]  = mask_idx[lgg[t][s]];
            }
        }

    const u32x4 vzero = {0u, 0u, 0u, 0u};

#define COMPUTE(TB) do {                                                            \
    _Pragma("unroll")                                                               \
    for (int s_ = 0; s_ < 2; ++s_) {                                                \
        if (wc + 4 * s_ < 7) {                                                      \
            f32x16 acc = {};                                                        \
            int r0_ = rr[TB][s_], ow0_ = oww[TB][s_], mv0_ = mv[TB][s_];            \
            _Pragma("unroll")                                                       \
            for (int p_ = 0; p_ < 9; ++p_) {                                        \
                int dh_ = p_ / 3, dw_ = p_ - dh_ * 3;                               \
                int wq_   = ow0_ + dw_;                                             \
                int base_ = ((r0_ + dh_) * WP + wq_) << 7;                          \
                int swz_  = (wq_ & 7) << 4;                                         \
                u32x4 bv[4];                                                        \
                _Pragma("unroll")                                                   \
                for (int kc_ = 0; kc_ < 4; ++kc_)                                   \
                    bv[kc_] = *reinterpret_cast<const u32x4*>(                      \
                        &xs[TB][0] + ((base_ + ((2 * kc_ + hi) << 4)) ^ swz_));     \
                if (mv0_ == p_) { bv[0]=vzero; bv[1]=vzero; bv[2]=vzero; bv[3]=vzero; } \
                _Pragma("unroll")                                                   \
                for (int kc_ = 0; kc_ < 4; ++kc_) {                                 \
                    acc = __builtin_amdgcn_mfma_f32_32x32x16_bf16(                  \
                        *reinterpret_cast<bf16x8*>(&af[p_][kc_]),                   \
                        *reinterpret_cast<bf16x8*>(&bv[kc_]), acc, 0, 0, 0);        \
                }                                                                   \
            }                                                                       \
            float* ob_ = out + (size_t)(b * On + wr * 32) * Ln + lgg[TB][s_];       \
            _Pragma("unroll")                                                       \
            for (int reg_ = 0; reg_ < 16; ++reg_) {                                 \
                int orow_ = (reg_ & 3) + 8 * (reg_ >> 2) + 4 * hi;                  \
                ob_[(size_t)orow_ * Ln] = acc[reg_];                                \
            }                                                                       \
        }                                                                           \
    }                                                                               \
} while (0)

    __syncthreads();            // vmcnt(0) drain: tile0 + A-hoist complete

    STAGE(1, rq * 4 + 2);       // issue tile-1 DMAs BEFORE tile-0 compute
    COMPUTE(0);

    __syncthreads();            // vmcnt(0) drain: tile1 staged
    COMPUTE(1);

#undef STAGE
#undef COMPUTE
}

// -----------------------------------------------------------------------------
extern "C" void kernel_launch(void* const* d_in, const int* in_sizes, int n_in,
                              void* d_out, int out_size, void* d_ws, size_t ws_size,
                              hipStream_t stream) {
    const float* x    = (const float*)d_in[0];
    const float* w    = (const float*)d_in[1];
    const int*   mask = (const int*)d_in[2];
    float* out = (float*)d_out;

    unsigned short* xps = (unsigned short*)d_ws;                     // 13,307,904 B
    unsigned short* wpk = (unsigned short*)((char*)d_ws + 13307904); // +73,728 B

    prep_kernel<<<948,     128, 0, stream>>>(x, w, xps, wpk);
    conv_pipe  <<<Bn * 28, 512, 0, stream>>>(xps, wpk, mask, out);
}